// Round 1
// baseline (28.858 us; speedup 1.0000x reference)
//
#include <hip/hip_runtime.h>
#include <math.h>

// NormalizingFlow: 32 chained Affine(2) layers over 4,194,304 2-D points.
// Key identity: the chain x <- W_i x + b_i composes into ONE affine map
//   x_out = M x + c,  M = W_31 ... W_0,  c = W_31(...(W_0*0+b_0)...)+b_31
// so the per-point work collapses from 32 matmuls to one 2x2 apply.
// log_det = sum_i log|det W_i| (slogdet's log-abs-det summed over flows).

#define NF_POINTS   4194304
#define NF_FLOWS    32

// ---------------------------------------------------------------------------
// Kernel 1: single thread composes the affine chain in f64 (more accurate
// than the reference's sequential f32 scan) and computes log_det.
// Writes [m00,m01,m10,m11,c0,c1] as f32 into d_ws; log_det into d_out tail.
// ---------------------------------------------------------------------------
__global__ void nf_compose_kernel(const float* __restrict__ W,   // [32,2,2]
                                  const float* __restrict__ B,   // [32,2]
                                  float* __restrict__ params,    // d_ws (6 floats)
                                  float* __restrict__ logdet_out)
{
    if (blockIdx.x != 0 || threadIdx.x != 0) return;

    double p00 = 1.0, p01 = 0.0, p10 = 0.0, p11 = 1.0;  // M accumulator
    double c0 = 0.0, c1 = 0.0;                           // bias accumulator
    double ld = 0.0;

    for (int i = 0; i < NF_FLOWS; ++i) {
        const double w00 = (double)W[i * 4 + 0];
        const double w01 = (double)W[i * 4 + 1];
        const double w10 = (double)W[i * 4 + 2];
        const double w11 = (double)W[i * 4 + 3];
        const double b0  = (double)B[i * 2 + 0];
        const double b1  = (double)B[i * 2 + 1];

        // x_new = W_i * (P x + c) + b_i  ->  P' = W_i P, c' = W_i c + b_i
        const double n00 = w00 * p00 + w01 * p10;
        const double n01 = w00 * p01 + w01 * p11;
        const double n10 = w10 * p00 + w11 * p10;
        const double n11 = w10 * p01 + w11 * p11;
        const double nc0 = w00 * c0 + w01 * c1 + b0;
        const double nc1 = w10 * c0 + w11 * c1 + b1;
        p00 = n00; p01 = n01; p10 = n10; p11 = n11;
        c0 = nc0; c1 = nc1;

        ld += log(fabs(w00 * w11 - w01 * w10));
    }

    params[0] = (float)p00; params[1] = (float)p01;
    params[2] = (float)p10; params[3] = (float)p11;
    params[4] = (float)c0;  params[5] = (float)c1;
    *logdet_out = (float)ld;
}

// ---------------------------------------------------------------------------
// Kernel 2: streaming apply. One float4 = two 2-D points (x0,y0,x1,y1).
// 16 B/lane coalesced loads+stores; grid-stride, 2048 blocks x 256 threads.
// ---------------------------------------------------------------------------
__global__ void __launch_bounds__(256)
nf_apply_kernel(const float4* __restrict__ in,
                float4* __restrict__ out,
                const float* __restrict__ params,
                int n4)
{
    const float m00 = params[0], m01 = params[1];
    const float m10 = params[2], m11 = params[3];
    const float c0  = params[4], c1  = params[5];

    const int stride = gridDim.x * blockDim.x;
    for (int i = blockIdx.x * blockDim.x + threadIdx.x; i < n4; i += stride) {
        const float4 v = in[i];
        float4 o;
        o.x = fmaf(m00, v.x, fmaf(m01, v.y, c0));
        o.y = fmaf(m10, v.x, fmaf(m11, v.y, c1));
        o.z = fmaf(m00, v.z, fmaf(m01, v.w, c0));
        o.w = fmaf(m10, v.z, fmaf(m11, v.w, c1));
        out[i] = o;
    }
}

extern "C" void kernel_launch(void* const* d_in, const int* in_sizes, int n_in,
                              void* d_out, int out_size, void* d_ws, size_t ws_size,
                              hipStream_t stream)
{
    const float* x = (const float*)d_in[0];   // [4194304, 2] f32
    const float* W = (const float*)d_in[1];   // [32, 2, 2]   f32
    const float* B = (const float*)d_in[2];   // [32, 2]      f32

    float* out    = (float*)d_out;            // 8388608 x_out floats + 1 log_det
    float* params = (float*)d_ws;             // 6 floats scratch

    // 1) Compose the affine chain + log_det (trivial, 1 thread).
    nf_compose_kernel<<<1, 64, 0, stream>>>(W, B, params, out + (size_t)NF_POINTS * 2);

    // 2) Apply y = M x + c over all points, 2 points per float4.
    const int n4 = NF_POINTS / 2;             // 2,097,152 float4s
    const int block = 256;
    const int grid = 2048;                    // grid-stride, ~4 iters/thread
    nf_apply_kernel<<<grid, block, 0, stream>>>((const float4*)x, (float4*)out,
                                                params, n4);
}

// Round 2
// 17.786 us; speedup vs baseline: 1.6225x; 1.6225x over previous
//
#include <hip/hip_runtime.h>
#include <math.h>

// NormalizingFlow: 32 chained Affine(2) layers over 4,194,304 2-D points.
// The chain x <- W_i x + b_i composes into ONE affine map
//   x_out = M x + c,  M = W_31...W_0,  c = W_31(...(W_0*0+b_0)...)+b_31
// log_det = sum_i log|det W_i|.
//
// Single fused kernel:
//  - thread 0 of each block composes M,c in f64 into LDS (dep chain ~0.2us,
//    concurrent across blocks; hidden under the prefetched first load)
//  - wave 1 of block 0 computes log_det in parallel (one log per lane)
//  - all threads stream float4s (2 points each), nontemporal stores.

#define NF_POINTS 4194304
#define NF_FLOWS  32

__global__ void __launch_bounds__(256)
nf_fused_kernel(const float4* __restrict__ in,
                float4* __restrict__ out,
                const float* __restrict__ W,   // [32,2,2]
                const float* __restrict__ B,   // [32,2]
                float* __restrict__ logdet_out,
                int n4)
{
    __shared__ float sp[6];

    const int tid    = threadIdx.x;
    const int stride = gridDim.x * blockDim.x;
    int i = blockIdx.x * blockDim.x + tid;

    // Prefetch the first element BEFORE the compose barrier: the HBM latency
    // of this load covers thread 0's compose chain.
    float4 v;
    const bool valid = (i < n4);
    if (valid) v = in[i];

    if (tid == 0) {
        // Compose the affine chain in f64 (more accurate than the reference's
        // sequential f32 scan).
        double p00 = 1.0, p01 = 0.0, p10 = 0.0, p11 = 1.0;
        double c0 = 0.0, c1 = 0.0;
        for (int f = 0; f < NF_FLOWS; ++f) {
            const double w00 = (double)W[f * 4 + 0];
            const double w01 = (double)W[f * 4 + 1];
            const double w10 = (double)W[f * 4 + 2];
            const double w11 = (double)W[f * 4 + 3];
            const double b0  = (double)B[f * 2 + 0];
            const double b1  = (double)B[f * 2 + 1];
            const double n00 = w00 * p00 + w01 * p10;
            const double n01 = w00 * p01 + w01 * p11;
            const double n10 = w10 * p00 + w11 * p10;
            const double n11 = w10 * p01 + w11 * p11;
            const double nc0 = w00 * c0 + w01 * c1 + b0;
            const double nc1 = w10 * c0 + w11 * c1 + b1;
            p00 = n00; p01 = n01; p10 = n10; p11 = n11;
            c0 = nc0; c1 = nc1;
        }
        sp[0] = (float)p00; sp[1] = (float)p01;
        sp[2] = (float)p10; sp[3] = (float)p11;
        sp[4] = (float)c0;  sp[5] = (float)c1;
    } else if (blockIdx.x == 0 && tid >= 64 && tid < 96) {
        // Wave 1, lanes 0..31: one log|det W_f| per lane, shuffle-reduce.
        // Runs concurrently with thread 0's compose (different wave).
        const int f = tid - 64;
        const double w00 = (double)W[f * 4 + 0];
        const double w01 = (double)W[f * 4 + 1];
        const double w10 = (double)W[f * 4 + 2];
        const double w11 = (double)W[f * 4 + 3];
        double ld = log(fabs(w00 * w11 - w01 * w10));
        for (int off = 16; off; off >>= 1)
            ld += __shfl_down(ld, off, 32);
        if (f == 0) *logdet_out = (float)ld;
    }
    __syncthreads();

    const float m00 = sp[0], m01 = sp[1];
    const float m10 = sp[2], m11 = sp[3];
    const float cc0 = sp[4], cc1 = sp[5];

    // Grid-stride streaming: exactly 4 iterations/thread at 2048x256.
    while (i < n4) {
        float4 o;
        o.x = fmaf(m00, v.x, fmaf(m01, v.y, cc0));
        o.y = fmaf(m10, v.x, fmaf(m11, v.y, cc1));
        o.z = fmaf(m00, v.z, fmaf(m01, v.w, cc0));
        o.w = fmaf(m10, v.z, fmaf(m11, v.w, cc1));
        __builtin_nontemporal_store(o.x, &out[i].x);
        __builtin_nontemporal_store(o.y, &out[i].y);
        __builtin_nontemporal_store(o.z, &out[i].z);
        __builtin_nontemporal_store(o.w, &out[i].w);
        i += stride;
        if (i < n4) v = in[i];
    }
}

extern "C" void kernel_launch(void* const* d_in, const int* in_sizes, int n_in,
                              void* d_out, int out_size, void* d_ws, size_t ws_size,
                              hipStream_t stream)
{
    const float* x = (const float*)d_in[0];   // [4194304, 2] f32
    const float* W = (const float*)d_in[1];   // [32, 2, 2]   f32
    const float* B = (const float*)d_in[2];   // [32, 2]      f32

    float* out = (float*)d_out;               // 8388608 x_out + 1 log_det

    const int n4 = NF_POINTS / 2;             // 2,097,152 float4s
    const int block = 256;
    const int grid = 2048;                    // 8 blocks/CU, 4 iters/thread

    nf_fused_kernel<<<grid, block, 0, stream>>>(
        (const float4*)x, (float4*)out, W, B,
        out + (size_t)NF_POINTS * 2, n4);
}